// Round 4
// baseline (65.247 us; speedup 1.0000x reference)
//
#include <hip/hip_runtime.h>
#include <math.h>

#define CDIM 2048
#define EDIM 64
#define BM   32
#define BK   64
#define KSPLIT 4
#define SEGK (CDIM / KSPLIT)   // 512
#define NIT  (SEGK / BK)       // 8
#define LDA  72                // fp16 elems per LDS row (144B, 16B-aligned, 4-way bank spread)
#define LDB  72
#define PREPB 8                // prep blocks (256 rows each)

// scales keep fp16 "lo" parts normal; product scale = 2^22
#define SCALE_H 1024.0f
#define SCALE_W 4096.0f
#define INV_SCALE (1.0f / 4194304.0f)

typedef float    f32x16 __attribute__((ext_vector_type(16)));
typedef _Float16 f16x8  __attribute__((ext_vector_type(8)));
typedef __fp16   cvt_t  __attribute__((ext_vector_type(2)));  // cvt_pkrtz return type

// ---- prep: coalesced load of W [2048][64], LDS transpose, scale*2^12 fp16 hi/lo split ->
//      whi/wlo [E][C]; per-block partial column sums-of-squares -> pnw[8][64] (deterministic)
__global__ void prep_w(const float* __restrict__ W,
                       unsigned short* __restrict__ whi,
                       unsigned short* __restrict__ wlo,
                       float* __restrict__ pnw) {
    __shared__ float tile[256][65];
    __shared__ float part[4][64];
    const int t = threadIdx.x;            // 256
    const int c0 = blockIdx.x * 256;
#pragma unroll
    for (int p = 0; p < 16; ++p) {
        int r = (t >> 4) + p * 16;
        float4 v = *reinterpret_cast<const float4*>(W + (size_t)(c0 + r) * EDIM + (t & 15) * 4);
        tile[r][(t & 15) * 4 + 0] = v.x;
        tile[r][(t & 15) * 4 + 1] = v.y;
        tile[r][(t & 15) * 4 + 2] = v.z;
        tile[r][(t & 15) * 4 + 3] = v.w;
    }
    __syncthreads();
    {
        int g = t >> 6, e = t & 63;
        float s = 0.f;
#pragma unroll
        for (int j = 0; j < 64; ++j) { float v = tile[g * 64 + j][e]; s += v * v; }
        part[g][e] = s;
    }
    __syncthreads();
    if (t < 64) pnw[blockIdx.x * EDIM + t] = part[0][t] + part[1][t] + part[2][t] + part[3][t];
    {
        int e2 = t >> 2, cs = t & 3;
#pragma unroll
        for (int u = 0; u < 4; ++u) {
            int rbase = cs * 64 + u * 16;
            unsigned int hw[8], lw[8];
#pragma unroll
            for (int j = 0; j < 8; ++j) {
                float v0 = tile[rbase + 2 * j][e2] * SCALE_W;
                float v1 = tile[rbase + 2 * j + 1][e2] * SCALE_W;
                cvt_t hh = __builtin_amdgcn_cvt_pkrtz(v0, v1);
                cvt_t ll = __builtin_amdgcn_cvt_pkrtz(v0 - (float)hh[0], v1 - (float)hh[1]);
                hw[j] = __builtin_bit_cast(unsigned int, hh);
                lw[j] = __builtin_bit_cast(unsigned int, ll);
            }
            uint4* dh = reinterpret_cast<uint4*>(whi + (size_t)e2 * CDIM + c0 + rbase);
            dh[0] = make_uint4(hw[0], hw[1], hw[2], hw[3]);
            dh[1] = make_uint4(hw[4], hw[5], hw[6], hw[7]);
            uint4* dl = reinterpret_cast<uint4*>(wlo + (size_t)e2 * CDIM + c0 + rbase);
            dl[0] = make_uint4(lw[0], lw[1], lw[2], lw[3]);
            dl[1] = make_uint4(lw[4], lw[5], lw[6], lw[7]);
        }
    }
}

// lgkm-only drained barrier: vmem prefetch stays in flight across it
#define BARRIER() { asm volatile("s_waitcnt lgkmcnt(0)" ::: "memory"); \
    __builtin_amdgcn_sched_barrier(0); __builtin_amdgcn_s_barrier(); \
    __builtin_amdgcn_sched_barrier(0); }

#define CVT2(vx, vy, HO, LO) { \
    nacc += (vx) * (vx) + (vy) * (vy); \
    float s0_ = (vx) * SCALE_H, s1_ = (vy) * SCALE_H; \
    cvt_t hh_ = __builtin_amdgcn_cvt_pkrtz(s0_, s1_); \
    cvt_t ll_ = __builtin_amdgcn_cvt_pkrtz(s0_ - (float)hh_[0], s1_ - (float)hh_[1]); \
    HO = __builtin_bit_cast(unsigned int, hh_); \
    LO = __builtin_bit_cast(unsigned int, ll_); }

#define K1_LOAD(IT) { \
    const float4* ga_ = reinterpret_cast<const float4*>(pA + (IT) * BK); \
    fa0 = ga_[0]; fa1 = ga_[1]; fa2 = ga_[2]; fa3 = ga_[3]; \
    const uint4* gh_ = reinterpret_cast<const uint4*>(pBh + (IT) * BK); \
    rb0 = gh_[0]; rb1 = gh_[1]; rb2 = gh_[2]; rb3 = gh_[3]; \
    const uint4* gl_ = reinterpret_cast<const uint4*>(pBl + (IT) * BK); \
    rb4 = gl_[0]; rb5 = gl_[1]; rb6 = gl_[2]; rb7 = gl_[3]; }

// ---- k1: split-K fused normalize+GEMM -> per-segment partial dots + partial row norms
__launch_bounds__(128, 3)
__global__ void gemm_splitk(const float* __restrict__ H,
                            const unsigned short* __restrict__ whi,
                            const unsigned short* __restrict__ wlo,
                            float* __restrict__ pdot,
                            float* __restrict__ pnorm,
                            int ntok) {
    __shared__ unsigned short a_hi[BM][LDA], a_lo[BM][LDA];
    __shared__ unsigned short b_hi[EDIM][LDB], b_lo[EDIM][LDB];
    const int t = threadIdx.x;            // 128
    const int row0 = blockIdx.x * BM;
    const int seg = blockIdx.y;
    const int kbase = seg * SEGK;
    const int lane = t & 63, wv = t >> 6;
    const int arow = lane & 31, kg = lane >> 5;
    const int bcol = wv * 32 + arow;
    const int srow = t >> 2, cseg = t & 3;
    const int be = t >> 1, bhs = t & 1;

    const float* pA = H + (size_t)(row0 + srow) * CDIM + kbase + cseg * 16;
    const unsigned short* pBh = whi + (size_t)be * CDIM + kbase + bhs * 32;
    const unsigned short* pBl = wlo + (size_t)be * CDIM + kbase + bhs * 32;

    f32x16 acc_hh, acc_hl, acc_lh;
#pragma unroll
    for (int i = 0; i < 16; ++i) { acc_hh[i] = 0.f; acc_hl[i] = 0.f; acc_lh[i] = 0.f; }
    float nacc = 0.f;
    float4 fa0, fa1, fa2, fa3;
    uint4 rb0, rb1, rb2, rb3, rb4, rb5, rb6, rb7;

    K1_LOAD(0);
    for (int it = 0; it < NIT; ++it) {
        if (it) BARRIER();                // prev readers done; prefetch stays in flight
        // convert A (waits its vmem via reg deps) + write LDS; copy B to LDS
        {
            unsigned int h0,h1,h2,h3,h4,h5,h6,h7, l0,l1,l2,l3,l4,l5,l6,l7;
            CVT2(fa0.x, fa0.y, h0, l0); CVT2(fa0.z, fa0.w, h1, l1);
            CVT2(fa1.x, fa1.y, h2, l2); CVT2(fa1.z, fa1.w, h3, l3);
            CVT2(fa2.x, fa2.y, h4, l4); CVT2(fa2.z, fa2.w, h5, l5);
            CVT2(fa3.x, fa3.y, h6, l6); CVT2(fa3.z, fa3.w, h7, l7);
            uint4* da = reinterpret_cast<uint4*>(&a_hi[srow][cseg * 16]);
            da[0] = make_uint4(h0, h1, h2, h3);
            da[1] = make_uint4(h4, h5, h6, h7);
            uint4* dl = reinterpret_cast<uint4*>(&a_lo[srow][cseg * 16]);
            dl[0] = make_uint4(l0, l1, l2, l3);
            dl[1] = make_uint4(l4, l5, l6, l7);
            uint4* dbh = reinterpret_cast<uint4*>(&b_hi[be][bhs * 32]);
            dbh[0] = rb0; dbh[1] = rb1; dbh[2] = rb2; dbh[3] = rb3;
            uint4* dbl = reinterpret_cast<uint4*>(&b_lo[be][bhs * 32]);
            dbl[0] = rb4; dbl[1] = rb5; dbl[2] = rb6; dbl[3] = rb7;
        }
        BARRIER();                        // writes visible
        if (it + 1 < NIT) K1_LOAD(it + 1);   // prefetch: covered by MFMA phase + barrier
#pragma unroll
        for (int kk = 0; kk < 4; ++kk) {
            f16x8 ah = *reinterpret_cast<const f16x8*>(&a_hi[arow][kk * 16 + kg * 8]);
            f16x8 al = *reinterpret_cast<const f16x8*>(&a_lo[arow][kk * 16 + kg * 8]);
            f16x8 bh = *reinterpret_cast<const f16x8*>(&b_hi[bcol][kk * 16 + kg * 8]);
            f16x8 bl = *reinterpret_cast<const f16x8*>(&b_lo[bcol][kk * 16 + kg * 8]);
            acc_hh = __builtin_amdgcn_mfma_f32_32x32x16_f16(ah, bh, acc_hh, 0, 0, 0);
            acc_hl = __builtin_amdgcn_mfma_f32_32x32x16_f16(ah, bl, acc_hl, 0, 0, 0);
            acc_lh = __builtin_amdgcn_mfma_f32_32x32x16_f16(al, bh, acc_lh, 0, 0, 0);
        }
    }

    nacc += __shfl_xor(nacc, 1);
    nacc += __shfl_xor(nacc, 2);
    if (cseg == 0) pnorm[(size_t)seg * ntok + row0 + srow] = nacc;

    float* pd = pdot + ((size_t)seg * ntok + row0) * EDIM;
#pragma unroll
    for (int r = 0; r < 16; ++r) {
        int rowl = (r & 3) + 8 * (r >> 2) + 4 * kg;
        pd[(size_t)rowl * EDIM + bcol] = acc_hh[r] + acc_hl[r] + acc_lh[r];
    }
}

// ---- k2: reduce segments + norms, logits, top-2/count/softmax epilogue, all outputs
__global__ void gating_fin(const float* __restrict__ pdot,
                           const float* __restrict__ pnorm,
                           const float* __restrict__ pnw,
                           const float* __restrict__ gates,
                           float* __restrict__ out_rw,
                           float* __restrict__ out_lg,
                           float* __restrict__ out_mk,
                           int ntok) {
    const int t = threadIdx.x;            // 128
    const int rr = t >> 2, q = t & 3, e0 = q * 16;
    const int row = blockIdx.x * 32 + rr;

    float ls[16];
#pragma unroll
    for (int i = 0; i < 16; ++i) ls[i] = 0.f;
#pragma unroll
    for (int s = 0; s < KSPLIT; ++s) {
        const float4* p = reinterpret_cast<const float4*>(pdot + ((size_t)s * ntok + row) * EDIM + e0);
#pragma unroll
        for (int i = 0; i < 4; ++i) {
            float4 v = p[i];
            ls[i*4+0] += v.x; ls[i*4+1] += v.y; ls[i*4+2] += v.z; ls[i*4+3] += v.w;
        }
    }
    float nh = 0.f;
#pragma unroll
    for (int s = 0; s < KSPLIT; ++s) nh += pnorm[(size_t)s * ntok + row];
    float invh = INV_SCALE / fmaxf(sqrtf(nh), 1e-12f);

    float w2[16];
#pragma unroll
    for (int i = 0; i < 16; ++i) w2[i] = 0.f;
#pragma unroll
    for (int b = 0; b < PREPB; ++b) {
        const float4* p = reinterpret_cast<const float4*>(pnw + b * EDIM + e0);
#pragma unroll
        for (int i = 0; i < 4; ++i) {
            float4 v = p[i];
            w2[i*4+0] += v.x; w2[i*4+1] += v.y; w2[i*4+2] += v.z; w2[i*4+3] += v.w;
        }
    }
    float ga[16];
#pragma unroll
    for (int i = 0; i < 4; ++i) {
        float4 v = reinterpret_cast<const float4*>(gates + e0)[i];
        ga[i*4+0] = v.x; ga[i*4+1] = v.y; ga[i*4+2] = v.z; ga[i*4+3] = v.w;
    }
    float lg[16];
#pragma unroll
    for (int i = 0; i < 16; ++i) {
        float invw = 1.f / fmaxf(sqrtf(w2[i]), 1e-12f);
        float sig = 1.f / (1.f + __expf(-ga[i]));
        lg[i] = ls[i] * invh * invw - sig;
    }
    float* plg = out_lg + (size_t)row * EDIM + e0;
#pragma unroll
    for (int i = 0; i < 4; ++i)
        *reinterpret_cast<float4*>(plg + i * 4) =
            make_float4(lg[i*4], lg[i*4+1], lg[i*4+2], lg[i*4+3]);

    // top-2 (index tiebreak = lax.top_k), active count, masked softmax
    float v1 = -INFINITY, v2 = -INFINITY;
    int i1 = 0x7fffffff, i2 = 0x7fffffff, cnt = 0;
#pragma unroll
    for (int j = 0; j < 16; ++j) {
        int e = e0 + j;
        float v = lg[j];
        cnt += (v > 0.f) ? 1 : 0;
        if (v > v1) { v2 = v1; i2 = i1; v1 = v; i1 = e; }
        else if (v > v2) { v2 = v; i2 = e; }
    }
#pragma unroll
    for (int st = 1; st <= 2; st <<= 1) {
        float w1 = __shfl_xor(v1, st);
        int   j1 = __shfl_xor(i1, st);
        float wv2 = __shfl_xor(v2, st);
        int   j2 = __shfl_xor(i2, st);
        int   cc = __shfl_xor(cnt, st);
        cnt += cc;
        bool g = (w1 > v1) || (w1 == v1 && j1 < i1);
        if (g) {
            bool g2 = (v1 > wv2) || (v1 == wv2 && i1 < j2);
            float nv2 = g2 ? v1 : wv2;
            int   ni2 = g2 ? i1 : j2;
            v1 = w1; i1 = j1; v2 = nv2; i2 = ni2;
        } else {
            bool g2 = (w1 > v2) || (w1 == v2 && j1 < i2);
            if (g2) { v2 = w1; i2 = j1; }
        }
    }
    bool act = cnt > 0;
    float rmax = act ? v1 : 0.f;
    float xs[16], ms[16];
    float wsum = 0.f;
#pragma unroll
    for (int j = 0; j < 16; ++j) {
        int e = e0 + j;
        float l = lg[j];
        float x, m;
        if (act) {
            bool sel = l > 0.f;
            m = sel ? 1.f : 0.f;
            x = sel ? __expf(l - rmax) : 0.f;
        } else {
            bool sel = (e == i1) || (e == i2);
            m = sel ? 1.f : 0.f;
            x = m;
        }
        xs[j] = x; ms[j] = m; wsum += x;
    }
    wsum += __shfl_xor(wsum, 1);
    wsum += __shfl_xor(wsum, 2);
    float invd = 1.f / wsum;
    float* prw = out_rw + (size_t)row * EDIM + e0;
    float* pmk = out_mk + (size_t)row * EDIM + e0;
#pragma unroll
    for (int p = 0; p < 4; ++p) {
        *reinterpret_cast<float4*>(prw + p * 4) =
            make_float4(xs[p*4] * invd, xs[p*4+1] * invd, xs[p*4+2] * invd, xs[p*4+3] * invd);
        *reinterpret_cast<float4*>(pmk + p * 4) =
            make_float4(ms[p*4], ms[p*4+1], ms[p*4+2], ms[p*4+3]);
    }
}

extern "C" void kernel_launch(void* const* d_in, const int* in_sizes, int n_in,
                              void* d_out, int out_size, void* d_ws, size_t ws_size,
                              hipStream_t stream) {
    const float* H     = (const float*)d_in[0];
    const float* Wm    = (const float*)d_in[1];
    const float* gates = (const float*)d_in[2];
    const int ntok = in_sizes[0] / CDIM;   // 16384
    const int nmb  = ntok / BM;            // 512

    unsigned short* whi = (unsigned short*)d_ws;
    unsigned short* wlo = whi + (size_t)EDIM * CDIM;
    float* pnw   = (float*)(wlo + (size_t)EDIM * CDIM);
    float* pdot  = pnw + PREPB * EDIM;
    float* pnorm = pdot + (size_t)KSPLIT * ntok * EDIM;

    float* out_rw = (float*)d_out;
    float* out_lg = out_rw + (size_t)ntok * EDIM;
    float* out_mk = out_lg + (size_t)ntok * EDIM;

    hipLaunchKernelGGL(prep_w, dim3(PREPB), dim3(256), 0, stream, Wm, whi, wlo, pnw);
    hipLaunchKernelGGL(gemm_splitk, dim3(nmb, KSPLIT), dim3(128), 0, stream,
                       H, whi, wlo, pdot, pnorm, ntok);
    hipLaunchKernelGGL(gating_fin, dim3(nmb), dim3(128), 0, stream,
                       pdot, pnorm, pnw, gates, out_rw, out_lg, out_mk, ntok);
}

// Round 5
// 38.558 us; speedup vs baseline: 1.6922x; 1.6922x over previous
//
#include <hip/hip_runtime.h>
#include <math.h>

#define CDIM 2048
#define EDIM 64
#define BM   32
#define WSEG 512          // K per wave (in-block split-K by 4 waves)
#define NITW 8            // iters of 64 k per wave
#define PREPB 8

// scales keep fp16 "lo" parts normal; product scale = 2^22
#define SCALE_H 1024.0f
#define SCALE_W 4096.0f
#define INV_SCALE (1.0f / 4194304.0f)

typedef float    f32x16 __attribute__((ext_vector_type(16)));
typedef float    f32x4v __attribute__((ext_vector_type(4)));
typedef _Float16 f16x8  __attribute__((ext_vector_type(8)));
typedef __fp16   cvt_t  __attribute__((ext_vector_type(2)));

// ---- prep: load W [2048][64] coalesced, LDS transpose, per-block col-norm partials,
//      and write B in MFMA-FRAGMENT order: bfrag[kc][nt][hl][lane][8 halves]
//      (kc = k/16, nt = expert half, hl = hi/lo split term). 512 KB total, L2-resident.
__global__ void prep_w(const float* __restrict__ W,
                       unsigned short* __restrict__ bfrag,
                       float* __restrict__ pnw) {
    __shared__ float tile[256][65];
    __shared__ float part[4][64];
    const int t = threadIdx.x;            // 256
    const int c0 = blockIdx.x * 256;
#pragma unroll
    for (int p = 0; p < 16; ++p) {
        int r = (t >> 4) + p * 16;
        float4 v = *reinterpret_cast<const float4*>(W + (size_t)(c0 + r) * EDIM + (t & 15) * 4);
        tile[r][(t & 15) * 4 + 0] = v.x;
        tile[r][(t & 15) * 4 + 1] = v.y;
        tile[r][(t & 15) * 4 + 2] = v.z;
        tile[r][(t & 15) * 4 + 3] = v.w;
    }
    __syncthreads();
    {
        int g = t >> 6, e = t & 63;
        float s = 0.f;
#pragma unroll
        for (int j = 0; j < 64; ++j) { float v = tile[g * 64 + j][e]; s += v * v; }
        part[g][e] = s;
    }
    __syncthreads();
    if (t < 64) pnw[blockIdx.x * EDIM + t] = part[0][t] + part[1][t] + part[2][t] + part[3][t];

    const int nt = t >> 7, hl = (t >> 6) & 1, lane = t & 63;
    const int e = nt * 32 + (lane & 31);
    const int kb = (lane >> 5) * 8;
#pragma unroll
    for (int s = 0; s < 16; ++s) {
        int kl = s * 16 + kb;
        unsigned int wds[4];
#pragma unroll
        for (int pj = 0; pj < 4; ++pj) {
            float v0 = tile[kl + 2 * pj][e] * SCALE_W;
            float v1 = tile[kl + 2 * pj + 1][e] * SCALE_W;
            cvt_t hh = __builtin_amdgcn_cvt_pkrtz(v0, v1);
            if (hl) {
                cvt_t ll = __builtin_amdgcn_cvt_pkrtz(v0 - (float)hh[0], v1 - (float)hh[1]);
                wds[pj] = __builtin_bit_cast(unsigned int, ll);
            } else {
                wds[pj] = __builtin_bit_cast(unsigned int, hh);
            }
        }
        size_t off = ((size_t)(blockIdx.x * 16 + s)) * 2048 + (size_t)nt * 1024 + (size_t)hl * 512 + (size_t)lane * 8;
        *reinterpret_cast<uint4*>(bfrag + off) = make_uint4(wds[0], wds[1], wds[2], wds[3]);
    }
}

// ---- main: 512 blocks x 256 thr (4 waves). Wave w = k-segment w of the block's 32 rows.
//      A: global_load_lds fp32 (contiguous 16 lines/inst, source-side XOR swizzle);
//      B: fragment-order direct loads (contiguous, L2). No barriers in K-loop.
__launch_bounds__(256, 2)
__global__ void gating_main(const float* __restrict__ H,
                            const unsigned short* __restrict__ bfrag,
                            const float* __restrict__ pnw,
                            const float* __restrict__ gates,
                            float* __restrict__ out_rw,
                            float* __restrict__ out_lg,
                            float* __restrict__ out_mk) {
    __shared__ float aS[4][32][64];      // [wave][row][64 floats]; 16B chunks swizzled: slot c holds chunk c^(row&7)
    __shared__ float red[4][32][68];
    __shared__ float normred[4][32];
    __shared__ float invw_s[64];
    __shared__ float sig_s[64];

    const int t = threadIdx.x;
    const int w = t >> 6;                 // wave = k-segment
    const int l = t & 63;
    const int row0 = blockIdx.x * BM;
    const int kg = l >> 5;
    const int arow = l & 31;
    const int srow4 = l >> 4;             // staging: row-subindex in 4-row group
    const int sch = l & 15;               // staging: dest 16B chunk

    if (t < 64) {
        float s2 = 0.f;
#pragma unroll
        for (int b = 0; b < PREPB; ++b) s2 += pnw[b * EDIM + t];
        invw_s[t] = 1.f / fmaxf(sqrtf(s2), 1e-12f);
        sig_s[t] = 1.f / (1.f + __expf(-gates[t]));
    }

    f32x16 acc[2][3];
#pragma unroll
    for (int a = 0; a < 2; ++a)
#pragma unroll
        for (int b = 0; b < 3; ++b)
#pragma unroll
            for (int i = 0; i < 16; ++i) acc[a][b][i] = 0.f;
    float nacc = 0.f;

    // one global_load_lds: 4 rows x 16 lanes x 16B contiguous per row; src chunk XOR-preswizzled
#define STAGE1(J, IT) { \
    const int row_ = 4 * (J) + srow4; \
    const float* src_ = H + (size_t)(row0 + row_) * CDIM + w * WSEG + (IT) * 64 + ((sch ^ (row_ & 7)) << 2); \
    __builtin_amdgcn_global_load_lds((const __attribute__((address_space(1))) unsigned int*)src_, \
                                     (__attribute__((address_space(3))) unsigned int*)&aS[w][4 * (J)][0], 16, 0, 0); }
#define STAGE(IT) { STAGE1(0, IT); STAGE1(1, IT); STAGE1(2, IT); STAGE1(3, IT); \
                    STAGE1(4, IT); STAGE1(5, IT); STAGE1(6, IT); STAGE1(7, IT); }

    STAGE(0);
#pragma unroll
    for (int it = 0; it < NITW; ++it) {
        asm volatile("s_waitcnt vmcnt(0)" ::: "memory");   // STAGE(it) landed in LDS
        __builtin_amdgcn_sched_barrier(0);
        // read this wave's A-frags for all 4 k16 steps (fp32), swizzled chunks
        f32x4v fr[8];
#pragma unroll
        for (int j = 0; j < 4; ++j) {
            int ca = (4 * j + 2 * kg) ^ (arow & 7);
            int cb = (4 * j + 2 * kg + 1) ^ (arow & 7);
            fr[2 * j]     = *reinterpret_cast<const f32x4v*>(&aS[w][arow][ca * 4]);
            fr[2 * j + 1] = *reinterpret_cast<const f32x4v*>(&aS[w][arow][cb * 4]);
        }
        asm volatile("s_waitcnt lgkmcnt(0)" ::: "memory"); // reads done before overwrite
        __builtin_amdgcn_sched_barrier(0);
        if (it + 1 < NITW) STAGE(it + 1);                  // async, covered by compute below

#pragma unroll
        for (int j = 0; j < 4; ++j) {
            float f0 = fr[2*j][0], f1 = fr[2*j][1], f2 = fr[2*j][2], f3 = fr[2*j][3];
            float f4 = fr[2*j+1][0], f5 = fr[2*j+1][1], f6 = fr[2*j+1][2], f7 = fr[2*j+1][3];
            nacc += f0*f0 + f1*f1 + f2*f2 + f3*f3 + f4*f4 + f5*f5 + f6*f6 + f7*f7;
            float s0 = f0*SCALE_H, s1 = f1*SCALE_H, s2 = f2*SCALE_H, s3 = f3*SCALE_H;
            float s4 = f4*SCALE_H, s5 = f5*SCALE_H, s6 = f6*SCALE_H, s7 = f7*SCALE_H;
            cvt_t h0 = __builtin_amdgcn_cvt_pkrtz(s0, s1);
            cvt_t h1 = __builtin_amdgcn_cvt_pkrtz(s2, s3);
            cvt_t h2 = __builtin_amdgcn_cvt_pkrtz(s4, s5);
            cvt_t h3 = __builtin_amdgcn_cvt_pkrtz(s6, s7);
            cvt_t l0 = __builtin_amdgcn_cvt_pkrtz(s0 - (float)h0[0], s1 - (float)h0[1]);
            cvt_t l1 = __builtin_amdgcn_cvt_pkrtz(s2 - (float)h1[0], s3 - (float)h1[1]);
            cvt_t l2 = __builtin_amdgcn_cvt_pkrtz(s4 - (float)h2[0], s5 - (float)h2[1]);
            cvt_t l3 = __builtin_amdgcn_cvt_pkrtz(s6 - (float)h3[0], s7 - (float)h3[1]);
            f16x8 ah = __builtin_bit_cast(f16x8, make_uint4(
                __builtin_bit_cast(unsigned int, h0), __builtin_bit_cast(unsigned int, h1),
                __builtin_bit_cast(unsigned int, h2), __builtin_bit_cast(unsigned int, h3)));
            f16x8 al = __builtin_bit_cast(f16x8, make_uint4(
                __builtin_bit_cast(unsigned int, l0), __builtin_bit_cast(unsigned int, l1),
                __builtin_bit_cast(unsigned int, l2), __builtin_bit_cast(unsigned int, l3)));

            const unsigned short* bb = bfrag + ((size_t)(w * 32 + it * 4 + j)) * 2048 + (size_t)l * 8;
            f16x8 bh0 = __builtin_bit_cast(f16x8, *reinterpret_cast<const uint4*>(bb));
            f16x8 bl0 = __builtin_bit_cast(f16x8, *reinterpret_cast<const uint4*>(bb + 512));
            f16x8 bh1 = __builtin_bit_cast(f16x8, *reinterpret_cast<const uint4*>(bb + 1024));
            f16x8 bl1 = __builtin_bit_cast(f16x8, *reinterpret_cast<const uint4*>(bb + 1536));

            acc[0][0] = __builtin_amdgcn_mfma_f32_32x32x16_f16(ah, bh0, acc[0][0], 0, 0, 0);
            acc[0][1] = __builtin_amdgcn_mfma_f32_32x32x16_f16(ah, bl0, acc[0][1], 0, 0, 0);
            acc[0][2] = __builtin_amdgcn_mfma_f32_32x32x16_f16(al, bh0, acc[0][2], 0, 0, 0);
            acc[1][0] = __builtin_amdgcn_mfma_f32_32x32x16_f16(ah, bh1, acc[1][0], 0, 0, 0);
            acc[1][1] = __builtin_amdgcn_mfma_f32_32x32x16_f16(ah, bl1, acc[1][1], 0, 0, 0);
            acc[1][2] = __builtin_amdgcn_mfma_f32_32x32x16_f16(al, bh1, acc[1][2], 0, 0, 0);
        }
    }

    // per-wave partial results -> LDS
#pragma unroll
    for (int nt = 0; nt < 2; ++nt)
#pragma unroll
        for (int r = 0; r < 16; ++r) {
            int rowl = (r & 3) + 8 * (r >> 2) + 4 * kg;
            red[w][rowl][nt * 32 + arow] = acc[nt][0][r] + acc[nt][1][r] + acc[nt][2][r];
        }
    nacc += __shfl_xor(nacc, 32);
    if (l < 32) normred[w][l] = nacc;
    __syncthreads();

    // ---- epilogue: 8 threads per row, 8 experts each
    const int rr = t >> 3, e0 = (t & 7) * 8;
    const int orow = row0 + rr;
    float nh = normred[0][rr] + normred[1][rr] + normred[2][rr] + normred[3][rr];
    float invh = INV_SCALE / fmaxf(sqrtf(nh), 1e-12f);
    float lg[8];
#pragma unroll
    for (int k2 = 0; k2 < 8; ++k2) {
        int e = e0 + k2;
        float s = red[0][rr][e] + red[1][rr][e] + red[2][rr][e] + red[3][rr][e];
        lg[k2] = s * invh * invw_s[e] - sig_s[e];
    }
    float* plg = out_lg + (size_t)orow * EDIM + e0;
    *reinterpret_cast<float4*>(plg)     = make_float4(lg[0], lg[1], lg[2], lg[3]);
    *reinterpret_cast<float4*>(plg + 4) = make_float4(lg[4], lg[5], lg[6], lg[7]);

    // top-2 (index tiebreak = lax.top_k), active count, masked softmax
    float v1 = -INFINITY, v2 = -INFINITY;
    int i1 = 0x7fffffff, i2 = 0x7fffffff, cnt = 0;
#pragma unroll
    for (int j = 0; j < 8; ++j) {
        int e = e0 + j;
        float v = lg[j];
        cnt += (v > 0.f) ? 1 : 0;
        if (v > v1) { v2 = v1; i2 = i1; v1 = v; i1 = e; }
        else if (v > v2) { v2 = v; i2 = e; }
    }
#pragma unroll
    for (int st = 1; st <= 4; st <<= 1) {
        float w1 = __shfl_xor(v1, st);
        int   j1 = __shfl_xor(i1, st);
        float wv2 = __shfl_xor(v2, st);
        int   j2 = __shfl_xor(i2, st);
        int   cc = __shfl_xor(cnt, st);
        cnt += cc;
        bool g = (w1 > v1) || (w1 == v1 && j1 < i1);
        if (g) {
            bool g2 = (v1 > wv2) || (v1 == wv2 && i1 < j2);
            float nv2 = g2 ? v1 : wv2;
            int   ni2 = g2 ? i1 : j2;
            v1 = w1; i1 = j1; v2 = nv2; i2 = ni2;
        } else {
            bool g2 = (w1 > v2) || (w1 == v2 && j1 < i2);
            if (g2) { v2 = w1; i2 = j1; }
        }
    }
    bool act = cnt > 0;
    float rmax = act ? v1 : 0.f;
    float xs[8], ms[8];
    float wsum = 0.f;
#pragma unroll
    for (int j = 0; j < 8; ++j) {
        int e = e0 + j;
        float lv = lg[j];
        float x, m;
        if (act) {
            bool sel = lv > 0.f;
            m = sel ? 1.f : 0.f;
            x = sel ? __expf(lv - rmax) : 0.f;
        } else {
            bool sel = (e == i1) || (e == i2);
            m = sel ? 1.f : 0.f;
            x = m;
        }
        xs[j] = x; ms[j] = m; wsum += x;
    }
    wsum += __shfl_xor(wsum, 1);
    wsum += __shfl_xor(wsum, 2);
    wsum += __shfl_xor(wsum, 4);
    float invd = 1.f / wsum;
    float* prw = out_rw + (size_t)orow * EDIM + e0;
    float* pmk = out_mk + (size_t)orow * EDIM + e0;
    *reinterpret_cast<float4*>(prw)     = make_float4(xs[0]*invd, xs[1]*invd, xs[2]*invd, xs[3]*invd);
    *reinterpret_cast<float4*>(prw + 4) = make_float4(xs[4]*invd, xs[5]*invd, xs[6]*invd, xs[7]*invd);
    *reinterpret_cast<float4*>(pmk)     = make_float4(ms[0], ms[1], ms[2], ms[3]);
    *reinterpret_cast<float4*>(pmk + 4) = make_float4(ms[4], ms[5], ms[6], ms[7]);
}

extern "C" void kernel_launch(void* const* d_in, const int* in_sizes, int n_in,
                              void* d_out, int out_size, void* d_ws, size_t ws_size,
                              hipStream_t stream) {
    const float* H     = (const float*)d_in[0];
    const float* Wm    = (const float*)d_in[1];
    const float* gates = (const float*)d_in[2];
    const int ntok = in_sizes[0] / CDIM;   // 16384

    unsigned short* bfrag = (unsigned short*)d_ws;          // 512 KB
    float* pnw = (float*)(bfrag + (size_t)128 * 2048);      // 8 x 64

    float* out_rw = (float*)d_out;
    float* out_lg = out_rw + (size_t)ntok * EDIM;
    float* out_mk = out_lg + (size_t)ntok * EDIM;

    hipLaunchKernelGGL(prep_w, dim3(PREPB), dim3(256), 0, stream, Wm, bfrag, pnw);
    hipLaunchKernelGGL(gating_main, dim3(ntok / BM), dim3(256), 0, stream,
                       H, bfrag, pnw, gates, out_rw, out_lg, out_mk);
}